// Round 4
// baseline (49.164 us; speedup 1.0000x reference)
//
#include <hip/hip_runtime.h>

// ClusteringLayer: q[n,k] = normalize_k( 1 / (1 + ||x_n - c_k||^2) )
// x: [65536,256] fp32, clusters: [256,256] fp32, out: [65536,256] fp32.
// R3: R2 design + the missing cross-wave row-sum reduction (psum in LDS).
// B resident in registers (wave owns 64 cols), X staged fp32->f16 via
// double-buffered swizzled LDS (coalesced 16B/lane), T14 async stage split.

typedef _Float16 f16x8 __attribute__((ext_vector_type(8)));
typedef _Float16 f16x4 __attribute__((ext_vector_type(4)));
typedef float    f32x4 __attribute__((ext_vector_type(4)));

#define DIM    256
#define NCLUST 256
#define BM     32      // rows per tile
#define NTILES 4       // tiles per block -> 128 rows/block

// ---------------------------------------------------------------------------
// Pre-kernel: blocks 0..127  -> clusters fp32 -> f16 16x16x32 B-fragment order
//             blocks 128..383 -> c2[j] = sum_d clusters[j][d]^2
// Fragment f = s*16 + t (s = kstep 0..7, t = col-tile 0..15); lane l holds
// B[col = t*16 + (l&15)][k = s*32 + (l>>4)*8 + v], v = 0..7.
// A uses the same (group,v)->k map, so any HW k-permutation cancels.
// ---------------------------------------------------------------------------
__global__ __launch_bounds__(64) void pre_kernel(const float* __restrict__ clusters,
                                                 _Float16* __restrict__ bfrag,
                                                 float* __restrict__ c2) {
    int b = blockIdx.x;
    int l = threadIdx.x;
    if (b < 128) {
        int s   = b >> 4;
        int t   = b & 15;
        int col = t * 16 + (l & 15);
        int k0  = s * 32 + (l >> 4) * 8;
        const f32x4* p = reinterpret_cast<const f32x4*>(clusters + col * DIM + k0);
        f32x4 a = p[0];
        f32x4 c = p[1];
        f16x8 h;
        h[0] = (_Float16)a[0]; h[1] = (_Float16)a[1];
        h[2] = (_Float16)a[2]; h[3] = (_Float16)a[3];
        h[4] = (_Float16)c[0]; h[5] = (_Float16)c[1];
        h[6] = (_Float16)c[2]; h[7] = (_Float16)c[3];
        reinterpret_cast<f16x8*>(bfrag)[b * 64 + l] = h;
    } else {
        int j = b - 128;
        const f32x4* p = reinterpret_cast<const f32x4*>(clusters + j * DIM);
        f32x4 v = p[l];
        float s = v[0] * v[0] + v[1] * v[1] + v[2] * v[2] + v[3] * v[3];
#pragma unroll
        for (int m = 32; m >= 1; m >>= 1) s += __shfl_xor(s, m, 64);
        if (l == 0) c2[j] = s;
    }
}

// ---------------------------------------------------------------------------
// Main kernel: 512 blocks x 256 threads (4 waves). Block owns 128 rows as
// 4 tiles of 32. Wave w owns cols [w*64, w*64+64) with B in registers.
// Row-normalizer = cross-wave sum via psum[4][BM] in LDS.
// ---------------------------------------------------------------------------
__global__ __launch_bounds__(256, 2) void cluster_kernel(const float* __restrict__ x,
                                                         const f16x8* __restrict__ bfrag,
                                                         const float* __restrict__ c2,
                                                         float* __restrict__ out) {
    __shared__ _Float16 Xs[2][BM * DIM];   // 2 x 16 KB, swizzled
    __shared__ float    x2s[2][BM];
    __shared__ float    psum[4][BM];       // per-wave partial row sums

    const int tid  = threadIdx.x;
    const int lane = tid & 63;
    const int wave = tid >> 6;
    const int cl   = lane & 15;
    const int g    = lane >> 4;
    const size_t rowbase = (size_t)blockIdx.x * (BM * NTILES);

    // ---- B fragments for this wave's 64 cols: 32 x 16B = 128 VGPRs, loaded once ----
    f16x8 breg[32];
#pragma unroll
    for (int s = 0; s < 8; ++s)
#pragma unroll
        for (int t = 0; t < 4; ++t)
            breg[s * 4 + t] = bfrag[(s * 16 + wave * 4 + t) * 64 + lane];

    float c2v[4];
#pragma unroll
    for (int t = 0; t < 4; ++t) c2v[t] = c2[(wave * 4 + t) * 16 + cl];

    f32x4 ld[8];

    // ================= prologue: stage tile 0 =================
#pragma unroll
    for (int i = 0; i < 8; ++i) {
        int idx = i * 256 + tid;
        int r = idx >> 6, c4 = idx & 63;
        ld[i] = *reinterpret_cast<const f32x4*>(x + (rowbase + r) * DIM + c4 * 4);
    }
#pragma unroll
    for (int i = 0; i < 8; ++i) {
        int idx = i * 256 + tid;
        int r = idx >> 6, c4 = idx & 63;
        f32x4 a = ld[i];
        float s = a[0]*a[0] + a[1]*a[1] + a[2]*a[2] + a[3]*a[3];
        s += __shfl_xor(s, 1, 64);  s += __shfl_xor(s, 2, 64);
        s += __shfl_xor(s, 4, 64);  s += __shfl_xor(s, 8, 64);
        s += __shfl_xor(s, 16, 64); s += __shfl_xor(s, 32, 64);
        if (lane == 0) x2s[0][r] = s;
        f16x4 h;
        h[0] = (_Float16)a[0]; h[1] = (_Float16)a[1];
        h[2] = (_Float16)a[2]; h[3] = (_Float16)a[3];
        int g16 = c4 >> 1, sub = c4 & 1;
        int byte = r * 512 + (((g16 ^ (r & 7))) << 4) + sub * 8;
        *reinterpret_cast<f16x4*>(reinterpret_cast<char*>(&Xs[0][0]) + byte) = h;
    }
    __syncthreads();

    // ================= main loop over tiles =================
#pragma unroll 1
    for (int it = 0; it < NTILES; ++it) {
        const int buf = it & 1;

        // ---- T14: issue next tile's global loads now (consumed after compute) ----
        if (it + 1 < NTILES) {
#pragma unroll
            for (int i = 0; i < 8; ++i) {
                int idx = i * 256 + tid;
                int r = idx >> 6, c4 = idx & 63;
                ld[i] = *reinterpret_cast<const f32x4*>(
                    x + (rowbase + (it + 1) * BM + r) * DIM + c4 * 4);
            }
        }

        // ---- compute 32 rows x 64 cols ----
        f32x4 acc[2][4] = {};
        const char* xb = reinterpret_cast<const char*>(&Xs[buf][0]);
        __builtin_amdgcn_s_setprio(1);
#pragma unroll
        for (int s = 0; s < 8; ++s) {
            f16x8 af[2];
#pragma unroll
            for (int rs = 0; rs < 2; ++rs) {
                int rr = rs * 16 + cl;
                int g16 = s * 4 + g;
                af[rs] = *reinterpret_cast<const f16x8*>(
                    xb + rr * 512 + ((g16 ^ (rr & 7)) << 4));
            }
#pragma unroll
            for (int rs = 0; rs < 2; ++rs)
#pragma unroll
                for (int t = 0; t < 4; ++t)
                    acc[rs][t] = __builtin_amdgcn_mfma_f32_16x16x32_f16(
                        af[rs], breg[s * 4 + t], acc[rs][t], 0, 0, 0);
        }
        __builtin_amdgcn_s_setprio(0);

        // ---- epilogue phase A: q, per-wave partial row sums -> psum ----
        // C/D layout: col = lane&15, row = (lane>>4)*4 + reg.
#pragma unroll
        for (int rs = 0; rs < 2; ++rs) {
            float rsum[4] = {0.f, 0.f, 0.f, 0.f};
#pragma unroll
            for (int j = 0; j < 4; ++j) {
                float x2j = x2s[buf][rs * 16 + g * 4 + j];
#pragma unroll
                for (int t = 0; t < 4; ++t) {
                    float d2 = 1.0f + x2j + c2v[t] - 2.0f * acc[rs][t][j];
                    float q  = __builtin_amdgcn_rcpf(d2);
                    acc[rs][t][j] = q;
                    rsum[j] += q;
                }
            }
#pragma unroll
            for (int j = 0; j < 4; ++j) {
                float v = rsum[j];
                v += __shfl_xor(v, 1, 64); v += __shfl_xor(v, 2, 64);
                v += __shfl_xor(v, 4, 64); v += __shfl_xor(v, 8, 64);
                if (cl == 0) psum[wave][rs * 16 + g * 4 + j] = v;
            }
        }
        __syncthreads();

        // ---- epilogue phase B: total row sum, normalize, store ----
#pragma unroll
        for (int rs = 0; rs < 2; ++rs) {
#pragma unroll
            for (int j = 0; j < 4; ++j) {
                int rloc = rs * 16 + g * 4 + j;
                float tot = psum[0][rloc] + psum[1][rloc]
                          + psum[2][rloc] + psum[3][rloc];
                float rn = __builtin_amdgcn_rcpf(tot);
                size_t row = rowbase + it * BM + rloc;
                float* op = out + row * NCLUST + wave * 64 + cl;
#pragma unroll
                for (int t = 0; t < 4; ++t) op[t * 16] = acc[rs][t][j] * rn;
            }
        }

        // ---- write staged tile it+1 into other buffer ----
        if (it + 1 < NTILES) {
#pragma unroll
            for (int i = 0; i < 8; ++i) {
                int idx = i * 256 + tid;
                int r = idx >> 6, c4 = idx & 63;
                f32x4 a = ld[i];
                float s = a[0]*a[0] + a[1]*a[1] + a[2]*a[2] + a[3]*a[3];
                s += __shfl_xor(s, 1, 64);  s += __shfl_xor(s, 2, 64);
                s += __shfl_xor(s, 4, 64);  s += __shfl_xor(s, 8, 64);
                s += __shfl_xor(s, 16, 64); s += __shfl_xor(s, 32, 64);
                if (lane == 0) x2s[buf ^ 1][r] = s;
                f16x4 h;
                h[0] = (_Float16)a[0]; h[1] = (_Float16)a[1];
                h[2] = (_Float16)a[2]; h[3] = (_Float16)a[3];
                int g16 = c4 >> 1, sub = c4 & 1;
                int byte = r * 512 + (((g16 ^ (r & 7))) << 4) + sub * 8;
                *reinterpret_cast<f16x4*>(
                    reinterpret_cast<char*>(&Xs[buf ^ 1][0]) + byte) = h;
            }
        }
        __syncthreads();
    }
}

extern "C" void kernel_launch(void* const* d_in, const int* in_sizes, int n_in,
                              void* d_out, int out_size, void* d_ws, size_t ws_size,
                              hipStream_t stream) {
    const float* x        = (const float*)d_in[0];
    const float* clusters = (const float*)d_in[1];
    float* out = (float*)d_out;

    _Float16* bfrag = (_Float16*)d_ws;                       // 128*64*16B = 128 KB
    float*    c2    = (float*)((char*)d_ws + 128 * 64 * 16); // 1 KB

    pre_kernel<<<384, 64, 0, stream>>>(clusters, bfrag, c2);

    int nrows = in_sizes[0] / DIM;              // 65536
    int grid  = nrows / (BM * NTILES);          // 512
    cluster_kernel<<<grid, 256, 0, stream>>>(x, (const f16x8*)bfrag, c2, out);
}